// Round 7
// baseline (10507.681 us; speedup 1.0000x reference)
//
#include <hip/hip_runtime.h>

typedef _Float16 f16;
typedef _Float16 f16x8 __attribute__((ext_vector_type(8)));
typedef float f32x4 __attribute__((ext_vector_type(4)));

#define NSTEPS 512
#define NBATCH 256
#define HID 256
#define NL 3
#define NBG 8              // batch groups of 32 rows
#define NNW 8              // N-split: 32 hidden units per WG
#define ROWS 32
#define DRING 8            // ring depth (steps)
#define PITCH 264          // f16 row pitch (528B: 2-way LDS aliasing only)
#define THREADS 256
#define BKB 15             // K-blocks of B kept in LDS (kb 15 in VGPRs)
#define FLAGSTRIDE 16      // ints per flag (64B padding -> own L2 line)

#define WPACK_OFF ((size_t)16384)               // flags occupy [0, 12288)
#define WPACK_ELEMS ((size_t)64*16*64*8)        // f16 per layer
#define WPACK_SZB (WPACK_ELEMS*2)               // 1 MiB per layer
#define RING_OFF (WPACK_OFF + 3*WPACK_SZB)
#define SLOT_F16 ((size_t)ROWS*HID)             // 8192 f16 = 16KB
#define RING_SZB ((size_t)NL*NBG*DRING*SLOT_F16*2)
#define WS_NEEDED (RING_OFF + RING_SZB)

__device__ __forceinline__ float sigm(float x){ return 1.f/(1.f+__expf(-x)); }
__device__ __forceinline__ float tanh_f(float x){ return 1.f - 2.f/(1.f+__expf(2.f*x)); }

// packed weights: [layer][nt(64)][kb(16)][lane(64)][e(8)] f16
// B-frag (mfma_f32_16x16x32_f16): col n = nt*16+(lane&15), k = kb*32+(lane>>4)*8+e.
// k<256 -> w_hh[n][k]; k>=256 -> w_ih[n][k-256] (0-padded past in_dim).
__global__ __launch_bounds__(256) void pack_weights(
    const float* __restrict__ wih0, const float* __restrict__ whh0,
    const float* __restrict__ wih1, const float* __restrict__ whh1,
    const float* __restrict__ wih2, const float* __restrict__ whh2,
    unsigned char* __restrict__ ws)
{
  int gid = blockIdx.x*256 + threadIdx.x;
  if (gid >= 3*64*16*64) return;
  int lane  = gid & 63;
  int kb    = (gid>>6) & 15;
  int nt    = (gid>>10) & 63;
  int layer = gid>>16;
  const float* whh = (layer==0)?whh0:((layer==1)?whh1:whh2);
  const float* wih = (layer==0)?wih0:((layer==1)?wih1:wih2);
  int indim = (layer==0)?12:256;
  int n  = nt*16 + (lane&15);
  int k0 = kb*32 + (lane>>4)*8;
  f16x8 v;
  #pragma unroll
  for (int e=0;e<8;++e){
    int k = k0+e;
    float x;
    if (k < HID) x = whh[n*HID + k];
    else { int ki = k-HID; x = (ki<indim)? wih[n*indim+ki] : 0.f; }
    v[e] = (f16)x;
  }
  f16* dst = (f16*)(ws + WPACK_OFF) + (size_t)layer*WPACK_ELEMS
           + ((size_t)(nt*16+kb)*64 + lane)*8;
  *(f16x8*)dst = v;
}

template<int KB>
__device__ __forceinline__ void gates_mfma(
    const f16* __restrict__ Hown, const f16* __restrict__ Hin,
    const f16* __restrict__ BstL,      // LDS-packed B, this WG (8 nt x BKB kb)
    const f16x8* __restrict__ b15,     // [4] kb=15 frags in regs
    int wm, int wn, int lane, int c16, f32x4* acc)
{
  const int arow = wm*16 + c16;
  #pragma unroll
  for (int kb=0; kb<KB; ++kb){
    const f16* ap = (kb<8) ? &Hown[arow*PITCH + kb*32 + (lane>>4)*8]
                           : &Hin [arow*PITCH + (kb-8)*32 + (lane>>4)*8];
    f16x8 a = *(const f16x8*)ap;
    #pragma unroll
    for (int G=0; G<4; ++G){
      f16x8 b;
      if (kb < BKB)
        b = ((const f16x8*)BstL)[ (size_t)((G*2+wn)*BKB + kb)*64 + lane ];
      else
        b = b15[G];
      acc[G] = __builtin_amdgcn_mfma_f32_16x16x32_f16(a, b, acc[G], 0,0,0);
    }
  }
}

// 192 WGs = 3 layers x 8 batch-groups x 8 N-groups. Weights LDS-stationary.
// bid = ((layer*8 + nw)<<3) | bg  -> all 24 WGs of a batch-group share an XCD
// (round-robin bid->XCD), so flags+rings are XCD-L2-local.
__global__ __launch_bounds__(THREADS) void lstm_ws(
    const float* __restrict__ input,
    const float* __restrict__ bih0, const float* __restrict__ bhh0,
    const float* __restrict__ bih1, const float* __restrict__ bhh1,
    const float* __restrict__ bih2, const float* __restrict__ bhh2,
    const float* __restrict__ wlin, const float* __restrict__ blin,
    unsigned char* __restrict__ ws, float* __restrict__ out)
{
  __shared__ __attribute__((aligned(16))) f16 Bst[8*BKB*64*8];   // 122880 B
  __shared__ __attribute__((aligned(16))) f16 Hown[ROWS*PITCH];  // 16896 B
  __shared__ __attribute__((aligned(16))) f16 Hin [ROWS*PITCH];  // 16896 B
  __shared__ float wlinLDS[HID];                                 // 1024 B

  const int tid  = threadIdx.x;
  const int w    = tid >> 6;          // 4 waves
  const int wm   = w >> 1, wn = w & 1;
  const int lane = tid & 63;
  const int c16  = lane & 15;
  const int r0   = (lane >> 4) * 4;
  const int bid  = blockIdx.x;
  const int bg   = bid & 7;
  const int nw   = (bid >> 3) & 7;
  const int layer= bid >> 6;
  const int rowsBase = bg * ROWS;
  const int unitBase = nw * 32;

  // padded flags: group (layer,bg) base = (layer*8+bg)*8 flags, 64B each
  int* flags = (int*)ws;
  int* fOwn  = flags + (layer*NBG + bg)*8*FLAGSTRIDE;
  int* fLow  = (layer>0)? flags + ((layer-1)*NBG + bg)*8*FLAGSTRIDE : fOwn;
  int* fUp   = (layer<2)? flags + ((layer+1)*NBG + bg)*8*FLAGSTRIDE : fOwn;

  const f16* wp = (const f16*)(ws + WPACK_OFF) + (size_t)layer*WPACK_ELEMS;
  f16* ringSelf = (f16*)(ws + RING_OFF) + (size_t)((layer*NBG + bg)*DRING)*SLOT_F16;
  f16* ringLow  = (layer>0)? (f16*)(ws + RING_OFF) + (size_t)(((layer-1)*NBG + bg)*DRING)*SLOT_F16 : (f16*)0;

  // ---- one-time: weights -> LDS (kb<15) and regs (kb 15) ----
  const f16x8* wpv = (const f16x8*)wp;                 // 16B units
  f16x8* Bv = (f16x8*)Bst;
  #pragma unroll
  for (int nl=0; nl<8; ++nl){
    int G = nl>>1, s = nl&1;
    int nt = G*16 + nw*2 + s;
    for (int idx=tid; idx<BKB*64; idx+=THREADS)
      Bv[(size_t)nl*BKB*64 + idx] = wpv[(size_t)nt*1024 + idx];
  }
  f16x8 b15[4];
  #pragma unroll
  for (int G=0; G<4; ++G){
    int nt = G*16 + nw*2 + wn;
    b15[G] = wpv[(size_t)nt*1024 + 15*64 + lane];
  }
  if (tid < HID) wlinLDS[tid] = wlin[tid];

  const float* BIH = (layer==0)?bih0:((layer==1)?bih1:bih2);
  const float* BHH = (layer==0)?bhh0:((layer==1)?bhh1:bhh2);
  float bias[4], cst[4];
  const int unit = unitBase + wn*16 + c16;
  #pragma unroll
  for (int G=0;G<4;++G){
    int n = G*HID + unit;
    bias[G] = BIH[n] + BHH[n];
    cst[G] = 0.f;                                   // reused as [q]
  }
  const float bl = blin[0];

  for (int i=tid; i<ROWS*PITCH; i+=THREADS){ Hown[i]=(f16)0.f; Hin[i]=(f16)0.f; }
  __syncthreads();

  for (int t=0; t<NSTEPS; ++t){
    // ---- wait (wave 0, <=24 lanes, role-masked): own>=t, low>=t+1, up>=t-7 ----
    if (w==0 && lane<24){
      const int role = lane>>3, idx = lane&7;
      bool active = (role==0) || (role==1 && layer>0) || (role==2 && layer<2);
      if (active){
        int* p   = (role==0)? fOwn + idx*FLAGSTRIDE
                 : (role==1)? fLow + idx*FLAGSTRIDE
                            : fUp  + idx*FLAGSTRIDE;
        int need = (role==0)? t : (role==1)? t+1 : t-DRING+1;
        int guard = 0;
        for(;;){
          int v = __hip_atomic_load(p, __ATOMIC_RELAXED, __HIP_MEMORY_SCOPE_AGENT);
          if (__all(v >= need)) break;
          if (++guard > (1<<20)) break;             // bounded: fail visibly
          __builtin_amdgcn_s_sleep(2);
        }
      }
    }
    __syncthreads();
    __builtin_amdgcn_fence(__ATOMIC_ACQUIRE, "agent");

    // ---- stage A tiles from rings ----
    if (t > 0){
      const f16x8* src = (const f16x8*)(ringSelf + (size_t)((t-1)&(DRING-1))*SLOT_F16);
      for (int i=tid; i<1024; i+=THREADS){
        int row = i>>5, c = i&31;
        ((f16x8*)Hown)[row*33 + c] = src[i];
      }
    }
    if (layer > 0){
      const f16x8* src = (const f16x8*)(ringLow + (size_t)(t&(DRING-1))*SLOT_F16);
      for (int i=tid; i<1024; i+=THREADS){
        int row = i>>5, c = i&31;
        ((f16x8*)Hin)[row*33 + c] = src[i];
      }
    } else {
      for (int idx=tid; idx<ROWS*12; idx+=THREADS){
        int r = idx/12, i = idx - r*12;
        Hin[r*PITCH + i] = (f16)input[((size_t)t*NBATCH + rowsBase + r)*12 + i];
      }
    }
    __syncthreads();

    // ---- fused linear head from h_{t-1} (layer 2; Hown holds h_{t-1}) ----
    if (layer==2 && t>0){
      int row = tid>>3, kc = tid&7;
      float s = 0.f;
      #pragma unroll
      for (int cc=0; cc<4; ++cc){
        f16x8 hv = *(const f16x8*)&Hown[row*PITCH + kc*32 + cc*8];
        #pragma unroll
        for (int j=0;j<8;++j) s += (float)hv[j] * wlinLDS[kc*32 + cc*8 + j];
      }
      s += __shfl_xor(s,1); s += __shfl_xor(s,2); s += __shfl_xor(s,4);
      if (kc==0) out[(size_t)(t-1)*NBATCH + rowsBase + row] = s + bl;
    }

    // ---- gates GEMM + cell ----
    f32x4 acc[4];
    #pragma unroll
    for (int G=0;G<4;++G){ f32x4 z={bias[G],bias[G],bias[G],bias[G]}; acc[G]=z; }
    if (layer==0) gates_mfma<9> (Hown, Hin, Bst, b15, wm, wn, lane, c16, acc);
    else          gates_mfma<16>(Hown, Hin, Bst, b15, wm, wn, lane, c16, acc);

    f16* slot = ringSelf + (size_t)(t&(DRING-1))*SLOT_F16;
    #pragma unroll
    for (int q=0;q<4;++q){
      float gi = sigm  (acc[0][q]);
      float gf = sigm  (acc[1][q]);
      float gg = tanh_f(acc[2][q]);
      float go = sigm  (acc[3][q]);
      float cv = gf*cst[q] + gi*gg; cst[q]=cv;
      float h  = go*tanh_f(cv);
      slot[(wm*16 + r0 + q)*HID + unit] = (f16)h;
    }
    __builtin_amdgcn_fence(__ATOMIC_RELEASE, "agent");   // order own ring stores
    __syncthreads();                                     // all waves done
    if (tid==0)
      __hip_atomic_store(fOwn + nw*FLAGSTRIDE, t+1,
                         __ATOMIC_RELEASE, __HIP_MEMORY_SCOPE_AGENT);
  }

  // ---- epilogue: out[511] from h_511 (layer 2) ----
  if (layer==2){
    if (w==0 && lane<8){
      int* p = fOwn + lane*FLAGSTRIDE;
      int guard = 0;
      for(;;){
        int v = __hip_atomic_load(p, __ATOMIC_RELAXED, __HIP_MEMORY_SCOPE_AGENT);
        if (__all(v >= NSTEPS)) break;
        if (++guard > (1<<20)) break;
        __builtin_amdgcn_s_sleep(2);
      }
    }
    __syncthreads();
    __builtin_amdgcn_fence(__ATOMIC_ACQUIRE, "agent");
    const f16x8* src = (const f16x8*)(ringSelf + (size_t)((NSTEPS-1)&(DRING-1))*SLOT_F16);
    for (int i=tid; i<1024; i+=THREADS){
      int row = i>>5, c = i&31;
      ((f16x8*)Hown)[row*33 + c] = src[i];
    }
    __syncthreads();
    int row = tid>>3, kc = tid&7;
    float s = 0.f;
    #pragma unroll
    for (int cc=0; cc<4; ++cc){
      f16x8 hv = *(const f16x8*)&Hown[row*PITCH + kc*32 + cc*8];
      #pragma unroll
      for (int j=0;j<8;++j) s += (float)hv[j] * wlinLDS[kc*32 + cc*8 + j];
    }
    s += __shfl_xor(s,1); s += __shfl_xor(s,2); s += __shfl_xor(s,4);
    if (kc==0) out[(size_t)(NSTEPS-1)*NBATCH + rowsBase + row] = s + bl;
  }
}

extern "C" void kernel_launch(void* const* d_in, const int* in_sizes, int n_in,
                              void* d_out, int out_size, void* d_ws, size_t ws_size,
                              hipStream_t stream)
{
  const float* input=(const float*)d_in[0];
  const float* wih0 =(const float*)d_in[1];
  const float* whh0 =(const float*)d_in[2];
  const float* bih0 =(const float*)d_in[3];
  const float* bhh0 =(const float*)d_in[4];
  const float* wih1 =(const float*)d_in[5];
  const float* whh1 =(const float*)d_in[6];
  const float* bih1 =(const float*)d_in[7];
  const float* bhh1 =(const float*)d_in[8];
  const float* wih2 =(const float*)d_in[9];
  const float* whh2 =(const float*)d_in[10];
  const float* bih2 =(const float*)d_in[11];
  const float* bhh2 =(const float*)d_in[12];
  const float* wlin =(const float*)d_in[13];
  const float* blin =(const float*)d_in[14];
  unsigned char* ws = (unsigned char*)d_ws;
  if (ws_size < WS_NEEDED) return;   // ~6.3 MB needed

  (void)hipMemsetAsync(ws, 0, WPACK_OFF, stream);   // flags (padded region)
  hipLaunchKernelGGL(pack_weights, dim3(768), dim3(256), 0, stream,
                     wih0,whh0,wih1,whh1,wih2,whh2, ws);
  hipLaunchKernelGGL(lstm_ws, dim3(NL*NBG*NNW), dim3(THREADS), 0, stream,
                     input, bih0,bhh0,bih1,bhh1,bih2,bhh2, wlin, blin,
                     ws, (float*)d_out);
}

// Round 8
// 3097.596 us; speedup vs baseline: 3.3922x; 3.3922x over previous
//
#include <hip/hip_runtime.h>

typedef _Float16 f16;
typedef _Float16 f16x8 __attribute__((ext_vector_type(8)));
typedef float f32x4 __attribute__((ext_vector_type(4)));
typedef unsigned long long u64;

#define NSTEPS 512
#define NBATCH 256
#define HID 256
#define NL 3
#define NBG 8              // batch groups of 32 rows
#define NNW 8              // N-split: 32 hidden units per WG
#define ROWS 32
#define DRING 8            // ring depth (steps)
#define PITCH 264          // f16 row pitch (528B: 2-way LDS aliasing only)
#define THREADS 256
#define BKB 15             // K-blocks of B kept in LDS (kb 15 in VGPRs)
#define FLAGSTRIDE 16      // ints per flag (64B padding)

#define WPACK_OFF ((size_t)16384)               // flags occupy [0, 12288)
#define WPACK_ELEMS ((size_t)64*16*64*8)        // f16 per layer
#define WPACK_SZB (WPACK_ELEMS*2)               // 1 MiB per layer
#define RING_OFF (WPACK_OFF + 3*WPACK_SZB)
#define SLOT_F16 ((size_t)ROWS*HID)             // 8192 f16 = 16KB = 2048 u64 granules
#define SLOT_Q 2048
#define RING_SZB ((size_t)NL*NBG*DRING*SLOT_F16*2)
#define WS_NEEDED (RING_OFF + RING_SZB)

__device__ __forceinline__ float sigm(float x){ return 1.f/(1.f+__expf(-x)); }
__device__ __forceinline__ float tanh_f(float x){ return 1.f - 2.f/(1.f+__expf(2.f*x)); }

// packed weights: [layer][nt(64)][kb(16)][lane(64)][e(8)] f16
// B-frag (mfma_f32_16x16x32_f16): col n = nt*16+(lane&15), k = kb*32+(lane>>4)*8+e.
// k<256 -> w_hh[n][k]; k>=256 -> w_ih[n][k-256] (0-padded past in_dim).
__global__ __launch_bounds__(256) void pack_weights(
    const float* __restrict__ wih0, const float* __restrict__ whh0,
    const float* __restrict__ wih1, const float* __restrict__ whh1,
    const float* __restrict__ wih2, const float* __restrict__ whh2,
    unsigned char* __restrict__ ws)
{
  int gid = blockIdx.x*256 + threadIdx.x;
  if (gid >= 3*64*16*64) return;
  int lane  = gid & 63;
  int kb    = (gid>>6) & 15;
  int nt    = (gid>>10) & 63;
  int layer = gid>>16;
  const float* whh = (layer==0)?whh0:((layer==1)?whh1:whh2);
  const float* wih = (layer==0)?wih0:((layer==1)?wih1:wih2);
  int indim = (layer==0)?12:256;
  int n  = nt*16 + (lane&15);
  int k0 = kb*32 + (lane>>4)*8;
  f16x8 v;
  #pragma unroll
  for (int e=0;e<8;++e){
    int k = k0+e;
    float x;
    if (k < HID) x = whh[n*HID + k];
    else { int ki = k-HID; x = (ki<indim)? wih[n*indim+ki] : 0.f; }
    v[e] = (f16)x;
  }
  f16* dst = (f16*)(ws + WPACK_OFF) + (size_t)layer*WPACK_ELEMS
           + ((size_t)(nt*16+kb)*64 + lane)*8;
  *(f16x8*)dst = v;
}

template<int KB>
__device__ __forceinline__ void gates_mfma(
    const f16* __restrict__ Hown, const f16* __restrict__ Hin,
    const f16* __restrict__ BstL,      // LDS-packed B, this WG (8 nt x BKB kb)
    const f16x8* __restrict__ b15,     // [4] kb=15 frags in regs
    int wm, int wn, int lane, int c16, f32x4* acc)
{
  const int arow = wm*16 + c16;
  #pragma unroll
  for (int kb=0; kb<KB; ++kb){
    const f16* ap = (kb<8) ? &Hown[arow*PITCH + kb*32 + (lane>>4)*8]
                           : &Hin [arow*PITCH + (kb-8)*32 + (lane>>4)*8];
    f16x8 a = *(const f16x8*)ap;
    #pragma unroll
    for (int G=0; G<4; ++G){
      f16x8 b;
      if (kb < BKB)
        b = ((const f16x8*)BstL)[ (size_t)((G*2+wn)*BKB + kb)*64 + lane ];
      else
        b = b15[G];
      acc[G] = __builtin_amdgcn_mfma_f32_16x16x32_f16(a, b, acc[G], 0,0,0);
    }
  }
}

// 192 WGs = 3 layers x 8 batch-groups x 8 N-groups. Weights LDS-stationary.
// ALL cross-WG data moves as 8B relaxed agent-scope atomics (LLC-coherent):
// no fences anywhere in the steady-state loop.
__global__ __launch_bounds__(THREADS) void lstm_ws(
    const float* __restrict__ input,
    const float* __restrict__ bih0, const float* __restrict__ bhh0,
    const float* __restrict__ bih1, const float* __restrict__ bhh1,
    const float* __restrict__ bih2, const float* __restrict__ bhh2,
    const float* __restrict__ wlin, const float* __restrict__ blin,
    unsigned char* __restrict__ ws, float* __restrict__ out)
{
  __shared__ __attribute__((aligned(16))) f16 Bst[8*BKB*64*8];   // 122880 B
  __shared__ __attribute__((aligned(16))) f16 Hown[ROWS*PITCH];  // 16896 B
  __shared__ __attribute__((aligned(16))) f16 Hin [ROWS*PITCH];  // 16896 B
  __shared__ __attribute__((aligned(16))) f16 Hstage[ROWS*32];   // 2048 B
  __shared__ float wlinLDS[HID];                                 // 1024 B

  const int tid  = threadIdx.x;
  const int w    = tid >> 6;          // 4 waves
  const int wm   = w >> 1, wn = w & 1;
  const int lane = tid & 63;
  const int c16  = lane & 15;
  const int r0   = (lane >> 4) * 4;
  const int bid  = blockIdx.x;
  const int bg   = bid & 7;
  const int nw   = (bid >> 3) & 7;
  const int layer= bid >> 6;
  const int rowsBase = bg * ROWS;
  const int unitBase = nw * 32;

  int* flags = (int*)ws;
  int* fOwn  = flags + (layer*NBG + bg)*8*FLAGSTRIDE;
  int* fLow  = (layer>0)? flags + ((layer-1)*NBG + bg)*8*FLAGSTRIDE : fOwn;
  int* fUp   = (layer<2)? flags + ((layer+1)*NBG + bg)*8*FLAGSTRIDE : fOwn;

  const f16* wp = (const f16*)(ws + WPACK_OFF) + (size_t)layer*WPACK_ELEMS;
  u64* ringSelfQ = (u64*)(ws + RING_OFF) + (size_t)((layer*NBG + bg)*DRING)*SLOT_Q;
  u64* ringLowQ  = (layer>0)? (u64*)(ws + RING_OFF) + (size_t)(((layer-1)*NBG + bg)*DRING)*SLOT_Q : (u64*)0;

  // ---- one-time: weights -> LDS (kb<15) and regs (kb 15) ----
  const f16x8* wpv = (const f16x8*)wp;
  f16x8* Bv = (f16x8*)Bst;
  #pragma unroll
  for (int nl=0; nl<8; ++nl){
    int G = nl>>1, s = nl&1;
    int nt = G*16 + nw*2 + s;
    for (int idx=tid; idx<BKB*64; idx+=THREADS)
      Bv[(size_t)nl*BKB*64 + idx] = wpv[(size_t)nt*1024 + idx];
  }
  f16x8 b15[4];
  #pragma unroll
  for (int G=0; G<4; ++G){
    int nt = G*16 + nw*2 + wn;
    b15[G] = wpv[(size_t)nt*1024 + 15*64 + lane];
  }
  if (tid < HID) wlinLDS[tid] = wlin[tid];

  const float* BIH = (layer==0)?bih0:((layer==1)?bih1:bih2);
  const float* BHH = (layer==0)?bhh0:((layer==1)?bhh1:bhh2);
  float bias[4], cst[4];
  const int unit = unitBase + wn*16 + c16;
  #pragma unroll
  for (int G=0;G<4;++G){
    int n = G*HID + unit;
    bias[G] = BIH[n] + BHH[n];
    cst[G] = 0.f;                                   // reused as [q]
  }
  const float bl = blin[0];

  for (int i=tid; i<ROWS*PITCH; i+=THREADS){ Hown[i]=(f16)0.f; Hin[i]=(f16)0.f; }
  __syncthreads();

  for (int t=0; t<NSTEPS; ++t){
    // ---- wait (wave 0, role-masked): own>=t, low>=t+1, up>=t-7 ----
    if (w==0 && lane<24){
      const int role = lane>>3, idx = lane&7;
      bool active = (role==0) || (role==1 && layer>0) || (role==2 && layer<2);
      if (active){
        int* p   = (role==0)? fOwn + idx*FLAGSTRIDE
                 : (role==1)? fLow + idx*FLAGSTRIDE
                            : fUp  + idx*FLAGSTRIDE;
        int need = (role==0)? t : (role==1)? t+1 : t-DRING+1;
        int guard = 0;
        for(;;){
          int v = __hip_atomic_load(p, __ATOMIC_RELAXED, __HIP_MEMORY_SCOPE_AGENT);
          if (__all(v >= need)) break;
          if (++guard > (1<<20)) break;             // bounded: fail visibly
          __builtin_amdgcn_s_sleep(2);
        }
      }
    }
    __syncthreads();
    asm volatile("" ::: "memory");   // pin staging loads after poll/barrier

    // ---- stage A tiles from rings (8B relaxed agent atomics, LLC-fresh) ----
    if (t > 0){
      const u64* src = ringSelfQ + (size_t)((t-1)&(DRING-1))*SLOT_Q;
      #pragma unroll
      for (int it=0; it<8; ++it){
        int i = tid + it*THREADS;                 // 2048 granules
        int row = i>>6, g = i&63;
        u64 v = __hip_atomic_load(src+i, __ATOMIC_RELAXED, __HIP_MEMORY_SCOPE_AGENT);
        *(u64*)&Hown[row*PITCH + g*4] = v;
      }
    }
    if (layer > 0){
      const u64* src = ringLowQ + (size_t)(t&(DRING-1))*SLOT_Q;
      #pragma unroll
      for (int it=0; it<8; ++it){
        int i = tid + it*THREADS;
        int row = i>>6, g = i&63;
        u64 v = __hip_atomic_load(src+i, __ATOMIC_RELAXED, __HIP_MEMORY_SCOPE_AGENT);
        *(u64*)&Hin[row*PITCH + g*4] = v;
      }
    } else {
      for (int idx=tid; idx<ROWS*12; idx+=THREADS){
        int r = idx/12, i = idx - r*12;
        Hin[r*PITCH + i] = (f16)input[((size_t)t*NBATCH + rowsBase + r)*12 + i];
      }
    }
    __syncthreads();

    // ---- fused linear head from h_{t-1} (layer 2) ----
    if (layer==2 && t>0){
      int row = tid>>3, kc = tid&7;
      float s = 0.f;
      #pragma unroll
      for (int cc=0; cc<4; ++cc){
        f16x8 hv = *(const f16x8*)&Hown[row*PITCH + kc*32 + cc*8];
        #pragma unroll
        for (int j=0;j<8;++j) s += (float)hv[j] * wlinLDS[kc*32 + cc*8 + j];
      }
      s += __shfl_xor(s,1); s += __shfl_xor(s,2); s += __shfl_xor(s,4);
      if (kc==0) out[(size_t)(t-1)*NBATCH + rowsBase + row] = s + bl;
    }

    // ---- gates GEMM + cell -> Hstage (32 rows x 32 local units) ----
    f32x4 acc[4];
    #pragma unroll
    for (int G=0;G<4;++G){ f32x4 z={bias[G],bias[G],bias[G],bias[G]}; acc[G]=z; }
    if (layer==0) gates_mfma<9> (Hown, Hin, Bst, b15, wm, wn, lane, c16, acc);
    else          gates_mfma<16>(Hown, Hin, Bst, b15, wm, wn, lane, c16, acc);

    const int lu = wn*16 + c16;      // local unit 0..31
    #pragma unroll
    for (int q=0;q<4;++q){
      float gi = sigm  (acc[0][q]);
      float gf = sigm  (acc[1][q]);
      float gg = tanh_f(acc[2][q]);
      float go = sigm  (acc[3][q]);
      float cv = gf*cst[q] + gi*gg; cst[q]=cv;
      float h  = go*tanh_f(cv);
      Hstage[(wm*16 + r0 + q)*32 + lu] = (f16)h;
    }
    __syncthreads();                  // Hstage complete

    // ---- stream Hstage -> ring slot t (one 8B relaxed atomic per thread) ----
    {
      int row = tid>>3, g = tid&7;
      u64 v = *(const u64*)&Hstage[row*32 + g*4];
      u64* dst = ringSelfQ + (size_t)(t&(DRING-1))*SLOT_Q + row*64 + (unitBase>>2) + g;
      __hip_atomic_store(dst, v, __ATOMIC_RELAXED, __HIP_MEMORY_SCOPE_AGENT);
    }
    asm volatile("s_waitcnt vmcnt(0)" ::: "memory");   // per-wave: stores at LLC
    __syncthreads();                                   // all waves done
    if (tid==0)
      __hip_atomic_store(fOwn + nw*FLAGSTRIDE, t+1,
                         __ATOMIC_RELAXED, __HIP_MEMORY_SCOPE_AGENT);
  }

  // ---- epilogue: out[511] from h_511 (layer 2) ----
  if (layer==2){
    if (w==0 && lane<8){
      int* p = fOwn + lane*FLAGSTRIDE;
      int guard = 0;
      for(;;){
        int v = __hip_atomic_load(p, __ATOMIC_RELAXED, __HIP_MEMORY_SCOPE_AGENT);
        if (__all(v >= NSTEPS)) break;
        if (++guard > (1<<20)) break;
        __builtin_amdgcn_s_sleep(2);
      }
    }
    __syncthreads();
    asm volatile("" ::: "memory");
    const u64* src = ringSelfQ + (size_t)((NSTEPS-1)&(DRING-1))*SLOT_Q;
    #pragma unroll
    for (int it=0; it<8; ++it){
      int i = tid + it*THREADS;
      int row = i>>6, g = i&63;
      u64 v = __hip_atomic_load(src+i, __ATOMIC_RELAXED, __HIP_MEMORY_SCOPE_AGENT);
      *(u64*)&Hown[row*PITCH + g*4] = v;
    }
    __syncthreads();
    int row = tid>>3, kc = tid&7;
    float s = 0.f;
    #pragma unroll
    for (int cc=0; cc<4; ++cc){
      f16x8 hv = *(const f16x8*)&Hown[row*PITCH + kc*32 + cc*8];
      #pragma unroll
      for (int j=0;j<8;++j) s += (float)hv[j] * wlinLDS[kc*32 + cc*8 + j];
    }
    s += __shfl_xor(s,1); s += __shfl_xor(s,2); s += __shfl_xor(s,4);
    if (kc==0) out[(size_t)(NSTEPS-1)*NBATCH + rowsBase + row] = s + bl;
  }
}

extern "C" void kernel_launch(void* const* d_in, const int* in_sizes, int n_in,
                              void* d_out, int out_size, void* d_ws, size_t ws_size,
                              hipStream_t stream)
{
  const float* input=(const float*)d_in[0];
  const float* wih0 =(const float*)d_in[1];
  const float* whh0 =(const float*)d_in[2];
  const float* bih0 =(const float*)d_in[3];
  const float* bhh0 =(const float*)d_in[4];
  const float* wih1 =(const float*)d_in[5];
  const float* whh1 =(const float*)d_in[6];
  const float* bih1 =(const float*)d_in[7];
  const float* bhh1 =(const float*)d_in[8];
  const float* wih2 =(const float*)d_in[9];
  const float* whh2 =(const float*)d_in[10];
  const float* bih2 =(const float*)d_in[11];
  const float* bhh2 =(const float*)d_in[12];
  const float* wlin =(const float*)d_in[13];
  const float* blin =(const float*)d_in[14];
  unsigned char* ws = (unsigned char*)d_ws;
  if (ws_size < WS_NEEDED) return;   // ~6.3 MB needed

  (void)hipMemsetAsync(ws, 0, WPACK_OFF, stream);   // flags
  hipLaunchKernelGGL(pack_weights, dim3(768), dim3(256), 0, stream,
                     wih0,whh0,wih1,whh1,wih2,whh2, ws);
  hipLaunchKernelGGL(lstm_ws, dim3(NL*NBG*NNW), dim3(THREADS), 0, stream,
                     input, bih0,bhh0,bih1,bhh1,bih2,bhh2, wlin, blin,
                     ws, (float*)d_out);
}